// Round 2
// baseline (145.205 us; speedup 1.0000x reference)
//
#include <hip/hip_runtime.h>
#include <hip/hip_bf16.h>

#define H 1024
#define V 50257
#define L 100
#define NPART 1024   // kD grid size == number of (m,s) partial pairs

// ---------- kA: attn logits (wave per row, 100 blocks x 64 threads) ----------

__global__ void kA_logits(const int* token, const float* hidden, const float* embedding,
                          const float* attn_w, const float* attn_b, float* ws_log) {
    int lane = threadIdx.x;                       // block == 1 wave
    int r = blockIdx.x;
    const float4* e4 = (const float4*)(embedding + (size_t)token[0] * H);
    const float4* h4 = (const float4*)hidden;
    const float4* wr = (const float4*)(attn_w + (size_t)r * (2 * H));
    float acc = 0.f;
    #pragma unroll
    for (int j = 0; j < 4; j++) {
        float4 w = wr[lane + 64 * j];
        float4 v = e4[lane + 64 * j];
        acc += w.x * v.x + w.y * v.y + w.z * v.z + w.w * v.w;
    }
    #pragma unroll
    for (int j = 0; j < 4; j++) {
        float4 w = wr[256 + lane + 64 * j];
        float4 v = h4[lane + 64 * j];
        acc += w.x * v.x + w.y * v.y + w.z * v.z + w.w * v.w;
    }
    #pragma unroll
    for (int off = 32; off > 0; off >>= 1) acc += __shfl_down(acc, off, 64);
    if (lane == 0) ws_log[r] = acc + attn_b[r];
}

// ---------- kB: softmax + attn_applied (LDS) + combine+relu (wave per row) ----------

__global__ void kB_softmax_combine(const int* token, const float* ws_log, const float* enc,
                                   const float* embedding, const float* comb_w,
                                   const float* comb_b, float* ws_x, float* out_attnw) {
    __shared__ float lg_s[L];
    __shared__ float aw_s[L];
    __shared__ float app_s[H];
    int t = threadIdx.x;
    if (t < L) lg_s[t] = ws_log[t];
    __syncthreads();
    float m = -1e30f;
    for (int l = 0; l < L; l++) m = fmaxf(m, lg_s[l]);
    float s = 0.f;
    for (int l = 0; l < L; l++) s += expf(lg_s[l] - m);
    if (t < L) aw_s[t] = expf(lg_s[t] - m) / s;
    __syncthreads();
    // attn_applied into LDS (each block redundantly; enc is L2-hot)
    for (int h = t; h < H; h += 256) {
        float a = 0.f;
        for (int l = 0; l < L; l++) a += aw_s[l] * enc[l * H + h];
        app_s[h] = a;
    }
    if (blockIdx.x == 0 && t < L) out_attnw[t] = aw_s[t];
    __syncthreads();
    // combine + relu: 8 rows per block, 2 per wave
    int lane = t & 63, wv = t >> 6;
    const float4* e4 = (const float4*)(embedding + (size_t)token[0] * H);
    const float4* a4 = (const float4*)app_s;
    #pragma unroll
    for (int i = 0; i < 2; i++) {
        int r = blockIdx.x * 8 + wv * 2 + i;
        const float4* wr = (const float4*)(comb_w + (size_t)r * (2 * H));
        float acc = 0.f;
        #pragma unroll
        for (int j = 0; j < 4; j++) {
            float4 w = wr[lane + 64 * j];
            float4 v = e4[lane + 64 * j];
            acc += w.x * v.x + w.y * v.y + w.z * v.z + w.w * v.w;
        }
        #pragma unroll
        for (int j = 0; j < 4; j++) {
            float4 w = wr[256 + lane + 64 * j];
            float4 v = a4[lane + 64 * j];
            acc += w.x * v.x + w.y * v.y + w.z * v.z + w.w * v.w;
        }
        #pragma unroll
        for (int off = 32; off > 0; off >>= 1) acc += __shfl_down(acc, off, 64);
        if (lane == 0) ws_x[r] = fmaxf(acc + comb_b[r], 0.0f);
    }
}

// ---------- kC: gi + gh + GRU gates, wave per hidden unit ----------

__global__ void kC_gru(const float* ws_x, const float* hidden,
                       const float* w_ih, const float* w_hh,
                       const float* b_ih, const float* b_hh,
                       float* out_h, float* ws_hn) {
    int lane = threadIdx.x & 63, wv = threadIdx.x >> 6;
    int h = blockIdx.x * 4 + wv;                  // 0..1023
    const float4* x4 = (const float4*)ws_x;
    const float4* h4 = (const float4*)hidden;
    float acc[6] = {0.f, 0.f, 0.f, 0.f, 0.f, 0.f};
    #pragma unroll
    for (int j = 0; j < 4; j++) {
        float4 xv = x4[lane + 64 * j];
        float4 hv = h4[lane + 64 * j];
        #pragma unroll
        for (int k = 0; k < 3; k++) {
            float4 w = ((const float4*)(w_ih + (size_t)(k * H + h) * H))[lane + 64 * j];
            acc[k] += w.x * xv.x + w.y * xv.y + w.z * xv.z + w.w * xv.w;
        }
        #pragma unroll
        for (int k = 0; k < 3; k++) {
            float4 w = ((const float4*)(w_hh + (size_t)(k * H + h) * H))[lane + 64 * j];
            acc[3 + k] += w.x * hv.x + w.y * hv.y + w.z * hv.z + w.w * hv.w;
        }
    }
    #pragma unroll
    for (int off = 32; off > 0; off >>= 1) {
        #pragma unroll
        for (int k = 0; k < 6; k++) acc[k] += __shfl_down(acc[k], off, 64);
    }
    if (lane == 0) {
        float ir = acc[0] + b_ih[h], iz = acc[1] + b_ih[H + h], in_ = acc[2] + b_ih[2 * H + h];
        float hr = acc[3] + b_hh[h], hz = acc[4] + b_hh[H + h], hn = acc[5] + b_hh[2 * H + h];
        float r = 1.f / (1.f + expf(-(ir + hr)));
        float z = 1.f / (1.f + expf(-(iz + hz)));
        float n = tanhf(in_ + r * hn);
        float h0 = hidden[h];
        float v = (1.f - z) * n + z * h0;
        out_h[h] = v;
        ws_hn[h] = v;
    }
}

// ---------- kD: logits = h_new @ out_w.T + out_b, 2 rows/wave/iter + online (m,s) ----------

__global__ void kD_outproj(const float* hn, const float* out_w, const float* out_b,
                           float* out_logits, float* ws_pm, float* ws_ps) {
    __shared__ float sm[4], ss[4];
    int lane = threadIdx.x & 63;
    int wv   = threadIdx.x >> 6;
    const float4* h4 = (const float4*)hn;
    float4 h0 = h4[lane], h1 = h4[lane + 64], h2 = h4[lane + 128], h3 = h4[lane + 192];
    float m = -1e30f, s = 0.f;
    int wid = blockIdx.x * 4 + wv;                // 0..4095
    for (int r0 = wid * 2; r0 < V; r0 += NPART * 8) {
        const float4* wr0 = (const float4*)(out_w + (size_t)r0 * H);
        float4 a = wr0[lane], b = wr0[lane + 64], c = wr0[lane + 128], d = wr0[lane + 192];
        float acc0 = a.x * h0.x + a.y * h0.y + a.z * h0.z + a.w * h0.w
                   + b.x * h1.x + b.y * h1.y + b.z * h1.z + b.w * h1.w
                   + c.x * h2.x + c.y * h2.y + c.z * h2.z + c.w * h2.w
                   + d.x * h3.x + d.y * h3.y + d.z * h3.z + d.w * h3.w;
        bool have2 = (r0 + 1) < V;
        float acc1 = 0.f;
        if (have2) {
            const float4* wr1 = (const float4*)(out_w + (size_t)(r0 + 1) * H);
            float4 e = wr1[lane], f = wr1[lane + 64], g = wr1[lane + 128], k = wr1[lane + 192];
            acc1 = e.x * h0.x + e.y * h0.y + e.z * h0.z + e.w * h0.w
                 + f.x * h1.x + f.y * h1.y + f.z * h1.z + f.w * h1.w
                 + g.x * h2.x + g.y * h2.y + g.z * h2.z + g.w * h2.w
                 + k.x * h3.x + k.y * h3.y + k.z * h3.z + k.w * h3.w;
        }
        #pragma unroll
        for (int off = 32; off > 0; off >>= 1) {
            acc0 += __shfl_down(acc0, off, 64);
            acc1 += __shfl_down(acc1, off, 64);
        }
        if (lane == 0) {
            float lg = acc0 + out_b[r0];
            out_logits[r0] = lg;
            float nm = fmaxf(m, lg);
            s = s * expf(m - nm) + expf(lg - nm);
            m = nm;
            if (have2) {
                float lg1 = acc1 + out_b[r0 + 1];
                out_logits[r0 + 1] = lg1;
                nm = fmaxf(m, lg1);
                s = s * expf(m - nm) + expf(lg1 - nm);
                m = nm;
            }
        }
    }
    if (lane == 0) { sm[wv] = m; ss[wv] = s; }
    __syncthreads();
    if (threadIdx.x == 0) {
        m = sm[0]; s = ss[0];
        #pragma unroll
        for (int i = 1; i < 4; i++) {
            float nm = fmaxf(m, sm[i]);
            s = s * expf(m - nm) + ss[i] * expf(sm[i] - nm);
            m = nm;
        }
        ws_pm[blockIdx.x] = m;
        ws_ps[blockIdx.x] = s;
    }
}

// ---------- kE: reduce partials (redundant per block) + in-place log_softmax ----------

__global__ void kE_finalize(const float* ws_pm, const float* ws_ps, float* out) {
    __shared__ float sm[4], ss[4], fm, fs;
    int t = threadIdx.x;
    float m = -1e30f, s = 0.f;
    for (int i = t; i < NPART; i += 256) {
        float pm = ws_pm[i], ps = ws_ps[i];
        float nm = fmaxf(m, pm);
        s = s * expf(m - nm) + ps * expf(pm - nm);
        m = nm;
    }
    #pragma unroll
    for (int off = 32; off > 0; off >>= 1) {
        float om = __shfl_down(m, off, 64);
        float os = __shfl_down(s, off, 64);
        float nm = fmaxf(m, om);
        s = s * expf(m - nm) + os * expf(om - nm);
        m = nm;
    }
    int lane = t & 63, wv = t >> 6;
    if (lane == 0) { sm[wv] = m; ss[wv] = s; }
    __syncthreads();
    if (t == 0) {
        m = sm[0]; s = ss[0];
        #pragma unroll
        for (int i = 1; i < 4; i++) {
            float nm = fmaxf(m, sm[i]);
            s = s * expf(m - nm) + ss[i] * expf(sm[i] - nm);
            m = nm;
        }
        fm = m; fs = logf(s);
    }
    __syncthreads();
    float M = fm, LS = fs;
    for (int v = blockIdx.x * 256 + t; v < V; v += gridDim.x * 256)
        out[v] = out[v] - M - LS;
}

// ---------- launch ----------

extern "C" void kernel_launch(void* const* d_in, const int* in_sizes, int n_in,
                              void* d_out, int out_size, void* d_ws, size_t ws_size,
                              hipStream_t stream) {
    const int*   token     = (const int*)d_in[0];
    const float* hidden    = (const float*)d_in[1];
    const float* enc       = (const float*)d_in[2];
    const float* embedding = (const float*)d_in[3];
    const float* attn_w    = (const float*)d_in[4];
    const float* attn_b    = (const float*)d_in[5];
    const float* comb_w    = (const float*)d_in[6];
    const float* comb_b    = (const float*)d_in[7];
    const float* w_ih      = (const float*)d_in[8];
    const float* w_hh      = (const float*)d_in[9];
    const float* b_ih      = (const float*)d_in[10];
    const float* b_hh      = (const float*)d_in[11];
    const float* out_w     = (const float*)d_in[12];
    const float* out_b     = (const float*)d_in[13];

    float* out = (float*)d_out;           // [0,V) log_softmax | [V,V+H) h_new | [V+H,V+H+L) attn_w
    float* ws  = (float*)d_ws;
    float* ws_log = ws;                   // 100
    float* ws_x   = ws + 128;             // 1024
    float* ws_pm  = ws + 1152;            // 1024
    float* ws_ps  = ws + 2176;            // 1024
    float* ws_hn  = ws + 3200;            // 1024

    kA_logits<<<dim3(L), dim3(64), 0, stream>>>(token, hidden, embedding,
                                                attn_w, attn_b, ws_log);
    kB_softmax_combine<<<dim3(128), dim3(256), 0, stream>>>(token, ws_log, enc, embedding,
                                                            comb_w, comb_b, ws_x, out + V + H);
    kC_gru<<<dim3(256), dim3(256), 0, stream>>>(ws_x, hidden, w_ih, w_hh, b_ih, b_hh,
                                                out + V, ws_hn);
    kD_outproj<<<dim3(NPART), dim3(256), 0, stream>>>(ws_hn, out_w, out_b, out, ws_pm, ws_ps);
    kE_finalize<<<dim3(128), dim3(256), 0, stream>>>(ws_pm, ws_ps, out);
}

// Round 3
// 58.387 us; speedup vs baseline: 2.4870x; 2.4870x over previous
//
#include <hip/hip_runtime.h>
#include <hip/hip_bf16.h>

#define H 1024
#define V 50257
#define L 100
#define NPART 1024   // kD grid size == number of (m,s) partial pairs

// ---------- kA: attn logits (wave per row, 100 blocks x 64 threads) ----------

__global__ void kA_logits(const int* token, const float* hidden, const float* embedding,
                          const float* attn_w, const float* attn_b, float* ws_log) {
    int lane = threadIdx.x;                       // block == 1 wave
    int r = blockIdx.x;
    const float4* e4 = (const float4*)(embedding + (size_t)token[0] * H);
    const float4* h4 = (const float4*)hidden;
    const float4* wr = (const float4*)(attn_w + (size_t)r * (2 * H));
    float acc = 0.f;
    #pragma unroll
    for (int j = 0; j < 4; j++) {
        float4 w = wr[lane + 64 * j];
        float4 v = e4[lane + 64 * j];
        acc += w.x * v.x + w.y * v.y + w.z * v.z + w.w * v.w;
    }
    #pragma unroll
    for (int j = 0; j < 4; j++) {
        float4 w = wr[256 + lane + 64 * j];
        float4 v = h4[lane + 64 * j];
        acc += w.x * v.x + w.y * v.y + w.z * v.z + w.w * v.w;
    }
    #pragma unroll
    for (int off = 32; off > 0; off >>= 1) acc += __shfl_down(acc, off, 64);
    if (lane == 0) ws_log[r] = acc + attn_b[r];
}

// ---------- kS: parallel softmax + l-parallel attn_applied ----------
// grid 16 x 256. Block b owns h-columns [b*64, b*64+64). Wave w covers l in [w*25, w*25+25).

__global__ void kS_softmax_apply(const float* ws_log, const float* enc,
                                 float* ws_app, float* out_attnw) {
    __shared__ float red[8];
    __shared__ float aw_s[128];
    __shared__ float part[4][64];
    int t = threadIdx.x, lane = t & 63, wv = t >> 6;

    float x = (t < L) ? ws_log[t] : -1e30f;
    float mv = x;
    #pragma unroll
    for (int off = 32; off > 0; off >>= 1) mv = fmaxf(mv, __shfl_down(mv, off, 64));
    if (lane == 0) red[wv] = mv;
    __syncthreads();
    float m = fmaxf(fmaxf(red[0], red[1]), fmaxf(red[2], red[3]));
    float e = (t < L) ? expf(x - m) : 0.f;
    float sv = e;
    #pragma unroll
    for (int off = 32; off > 0; off >>= 1) sv += __shfl_down(sv, off, 64);
    if (lane == 0) red[4 + wv] = sv;
    __syncthreads();
    float s = red[4] + red[5] + red[6] + red[7];
    float aw = e / s;
    if (t < 128) aw_s[t] = aw;                    // zero-padded past L
    if (blockIdx.x == 0 && t < L) out_attnw[t] = aw;
    __syncthreads();

    int h = blockIdx.x * 64 + lane;
    float acc = 0.f;
    #pragma unroll
    for (int i = 0; i < 25; i++) {
        int l = wv * 25 + i;
        acc += aw_s[l] * enc[l * H + h];
    }
    part[wv][lane] = acc;
    __syncthreads();
    if (wv == 0)
        ws_app[h] = part[0][lane] + part[1][lane] + part[2][lane] + part[3][lane];
}

// ---------- kComb: x = relu(concat(emb, applied) @ comb_w.T + comb_b), wave per row ----------

__global__ void kComb(const int* token, const float* embedding, const float* ws_app,
                      const float* comb_w, const float* comb_b, float* ws_x) {
    int lane = threadIdx.x & 63, wv = threadIdx.x >> 6;
    int r = blockIdx.x * 4 + wv;                  // grid 256 -> 1024 rows
    const float4* e4 = (const float4*)(embedding + (size_t)token[0] * H);
    const float4* a4 = (const float4*)ws_app;
    const float4* wr = (const float4*)(comb_w + (size_t)r * (2 * H));
    float acc = 0.f;
    #pragma unroll
    for (int j = 0; j < 4; j++) {
        float4 w = wr[lane + 64 * j];
        float4 v = e4[lane + 64 * j];
        acc += w.x * v.x + w.y * v.y + w.z * v.z + w.w * v.w;
    }
    #pragma unroll
    for (int j = 0; j < 4; j++) {
        float4 w = wr[256 + lane + 64 * j];
        float4 v = a4[lane + 64 * j];
        acc += w.x * v.x + w.y * v.y + w.z * v.z + w.w * v.w;
    }
    #pragma unroll
    for (int off = 32; off > 0; off >>= 1) acc += __shfl_down(acc, off, 64);
    if (lane == 0) ws_x[r] = fmaxf(acc + comb_b[r], 0.0f);
}

// ---------- kC: gi + gh + GRU gates, wave per hidden unit ----------

__global__ void kC_gru(const float* ws_x, const float* hidden,
                       const float* w_ih, const float* w_hh,
                       const float* b_ih, const float* b_hh,
                       float* out_h, float* ws_hn) {
    int lane = threadIdx.x & 63, wv = threadIdx.x >> 6;
    int h = blockIdx.x * 4 + wv;                  // 0..1023
    const float4* x4 = (const float4*)ws_x;
    const float4* h4 = (const float4*)hidden;
    float acc[6] = {0.f, 0.f, 0.f, 0.f, 0.f, 0.f};
    #pragma unroll
    for (int j = 0; j < 4; j++) {
        float4 xv = x4[lane + 64 * j];
        float4 hv = h4[lane + 64 * j];
        #pragma unroll
        for (int k = 0; k < 3; k++) {
            float4 w = ((const float4*)(w_ih + (size_t)(k * H + h) * H))[lane + 64 * j];
            acc[k] += w.x * xv.x + w.y * xv.y + w.z * xv.z + w.w * xv.w;
        }
        #pragma unroll
        for (int k = 0; k < 3; k++) {
            float4 w = ((const float4*)(w_hh + (size_t)(k * H + h) * H))[lane + 64 * j];
            acc[3 + k] += w.x * hv.x + w.y * hv.y + w.z * hv.z + w.w * hv.w;
        }
    }
    #pragma unroll
    for (int off = 32; off > 0; off >>= 1) {
        #pragma unroll
        for (int k = 0; k < 6; k++) acc[k] += __shfl_down(acc[k], off, 64);
    }
    if (lane == 0) {
        float ir = acc[0] + b_ih[h], iz = acc[1] + b_ih[H + h], in_ = acc[2] + b_ih[2 * H + h];
        float hr = acc[3] + b_hh[h], hz = acc[4] + b_hh[H + h], hn = acc[5] + b_hh[2 * H + h];
        float r = 1.f / (1.f + expf(-(ir + hr)));
        float z = 1.f / (1.f + expf(-(iz + hz)));
        float n = tanhf(in_ + r * hn);
        float h0 = hidden[h];
        float v = (1.f - z) * n + z * h0;
        out_h[h] = v;
        ws_hn[h] = v;
    }
}

// ---------- kD: logits = h_new @ out_w.T + out_b, 4 rows/wave/iter + online (m,s) ----------

__global__ void kD_outproj(const float* hn, const float* out_w, const float* out_b,
                           float* out_logits, float* ws_pm, float* ws_ps) {
    __shared__ float sm[4], ss[4];
    int lane = threadIdx.x & 63;
    int wv   = threadIdx.x >> 6;
    const float4* h4 = (const float4*)hn;
    float4 h0 = h4[lane], h1 = h4[lane + 64], h2 = h4[lane + 128], h3 = h4[lane + 192];
    float m = -1e30f, s = 0.f;
    int wid = blockIdx.x * 4 + wv;                // 0..4095
    for (int r0 = wid * 4; r0 < V; r0 += NPART * 16) {
        float acc[4] = {0.f, 0.f, 0.f, 0.f};
        #pragma unroll
        for (int i = 0; i < 4; i++) {
            int r = r0 + i;
            if (r < V) {
                const float4* wr = (const float4*)(out_w + (size_t)r * H);
                float4 a = wr[lane], b = wr[lane + 64], c = wr[lane + 128], d = wr[lane + 192];
                acc[i] = a.x * h0.x + a.y * h0.y + a.z * h0.z + a.w * h0.w
                       + b.x * h1.x + b.y * h1.y + b.z * h1.z + b.w * h1.w
                       + c.x * h2.x + c.y * h2.y + c.z * h2.z + c.w * h2.w
                       + d.x * h3.x + d.y * h3.y + d.z * h3.z + d.w * h3.w;
            }
        }
        #pragma unroll
        for (int off = 32; off > 0; off >>= 1) {
            #pragma unroll
            for (int i = 0; i < 4; i++) acc[i] += __shfl_down(acc[i], off, 64);
        }
        if (lane == 0) {
            #pragma unroll
            for (int i = 0; i < 4; i++) {
                int r = r0 + i;
                if (r < V) {
                    float lg = acc[i] + out_b[r];
                    out_logits[r] = lg;
                    float nm = fmaxf(m, lg);
                    s = s * expf(m - nm) + expf(lg - nm);
                    m = nm;
                }
            }
        }
    }
    if (lane == 0) { sm[wv] = m; ss[wv] = s; }
    __syncthreads();
    if (threadIdx.x == 0) {
        m = sm[0]; s = ss[0];
        #pragma unroll
        for (int i = 1; i < 4; i++) {
            float nm = fmaxf(m, sm[i]);
            s = s * expf(m - nm) + ss[i] * expf(sm[i] - nm);
            m = nm;
        }
        ws_pm[blockIdx.x] = m;
        ws_ps[blockIdx.x] = s;
    }
}

// ---------- kE: reduce partials (redundant per block) + in-place log_softmax ----------

__global__ void kE_finalize(const float* ws_pm, const float* ws_ps, float* out) {
    __shared__ float sm[4], ss[4], fm, fs;
    int t = threadIdx.x;
    float m = -1e30f, s = 0.f;
    for (int i = t; i < NPART; i += 256) {
        float pm = ws_pm[i], ps = ws_ps[i];
        float nm = fmaxf(m, pm);
        s = s * expf(m - nm) + ps * expf(pm - nm);
        m = nm;
    }
    #pragma unroll
    for (int off = 32; off > 0; off >>= 1) {
        float om = __shfl_down(m, off, 64);
        float os = __shfl_down(s, off, 64);
        float nm = fmaxf(m, om);
        s = s * expf(m - nm) + os * expf(om - nm);
        m = nm;
    }
    int lane = t & 63, wv = t >> 6;
    if (lane == 0) { sm[wv] = m; ss[wv] = s; }
    __syncthreads();
    if (t == 0) {
        m = sm[0]; s = ss[0];
        #pragma unroll
        for (int i = 1; i < 4; i++) {
            float nm = fmaxf(m, sm[i]);
            s = s * expf(m - nm) + ss[i] * expf(sm[i] - nm);
            m = nm;
        }
        fm = m; fs = logf(s);
    }
    __syncthreads();
    float M = fm, LS = fs;
    for (int v = blockIdx.x * 256 + t; v < V; v += gridDim.x * 256)
        out[v] = out[v] - M - LS;
}

// ---------- launch ----------

extern "C" void kernel_launch(void* const* d_in, const int* in_sizes, int n_in,
                              void* d_out, int out_size, void* d_ws, size_t ws_size,
                              hipStream_t stream) {
    const int*   token     = (const int*)d_in[0];
    const float* hidden    = (const float*)d_in[1];
    const float* enc       = (const float*)d_in[2];
    const float* embedding = (const float*)d_in[3];
    const float* attn_w    = (const float*)d_in[4];
    const float* attn_b    = (const float*)d_in[5];
    const float* comb_w    = (const float*)d_in[6];
    const float* comb_b    = (const float*)d_in[7];
    const float* w_ih      = (const float*)d_in[8];
    const float* w_hh      = (const float*)d_in[9];
    const float* b_ih      = (const float*)d_in[10];
    const float* b_hh      = (const float*)d_in[11];
    const float* out_w     = (const float*)d_in[12];
    const float* out_b     = (const float*)d_in[13];

    float* out = (float*)d_out;           // [0,V) log_softmax | [V,V+H) h_new | [V+H,V+H+L) attn_w
    float* ws  = (float*)d_ws;
    float* ws_log = ws;                   // 100
    float* ws_app = ws + 128;             // 1024
    float* ws_x   = ws + 1152;            // 1024
    float* ws_pm  = ws + 2176;            // 1024
    float* ws_ps  = ws + 3200;            // 1024
    float* ws_hn  = ws + 4224;            // 1024

    kA_logits<<<dim3(L), dim3(64), 0, stream>>>(token, hidden, embedding,
                                                attn_w, attn_b, ws_log);
    kS_softmax_apply<<<dim3(16), dim3(256), 0, stream>>>(ws_log, enc, ws_app, out + V + H);
    kComb<<<dim3(256), dim3(256), 0, stream>>>(token, embedding, ws_app,
                                               comb_w, comb_b, ws_x);
    kC_gru<<<dim3(256), dim3(256), 0, stream>>>(ws_x, hidden, w_ih, w_hh, b_ih, b_hh,
                                                out + V, ws_hn);
    kD_outproj<<<dim3(NPART), dim3(256), 0, stream>>>(ws_hn, out_w, out_b, out, ws_pm, ws_ps);
    kE_finalize<<<dim3(128), dim3(256), 0, stream>>>(ws_pm, ws_ps, out);
}